// Round 1
// baseline (414.151 us; speedup 1.0000x reference)
//
#include <hip/hip_runtime.h>

#define B_    2
#define S_    2048
#define H_    16
#define HS_   128
#define HID_  2048
#define N_QKV 6144
#define SCALE_Q 0.08838834764831845f  // 1/sqrt(128)

typedef unsigned short ushort_t;
typedef __attribute__((ext_vector_type(8))) __bf16 bf16x8;
typedef __attribute__((ext_vector_type(4))) float f32x4;

__device__ __forceinline__ float bf2f(ushort_t u) {
  union { unsigned int i; float f; } x; x.i = ((unsigned int)u) << 16; return x.f;
}
__device__ __forceinline__ ushort_t f2bf(float f) {
  union { float f; unsigned int i; } x; x.f = f;
  unsigned int u = x.i;
  u += 0x7fffu + ((u >> 16) & 1u);   // RNE
  return (ushort_t)(u >> 16);
}
// async global->LDS, 16B per lane; LDS dest = wave-uniform base + lane*16
__device__ __forceinline__ void gload16(const ushort_t* g, ushort_t* l) {
  __builtin_amdgcn_global_load_lds(
      (__attribute__((address_space(1))) void*)g,
      (__attribute__((address_space(3))) void*)l, 16, 0, 0);
}
// raw barrier with compiler memory fence on both sides: s_barrier intrinsic is
// IntrNoMem, so without the asm clobbers LLVM may hoist ds_read/global_load_lds
// across it (rule #18/#21 hazard class).
__device__ __forceinline__ void barrier_raw() {
  asm volatile("" ::: "memory");
  __builtin_amdgcn_s_barrier();
  asm volatile("" ::: "memory");
}

// ---------------- fused prep: X->bf16 conv + both weight transposes ----------------
// blocks [0,4096): conv (8 floats/thread)
// blocks [4096,7168): Wqkv (2048x6144) -> WqkvT (6144x2048) bf16, 64x64 tiles
// blocks [7168,8192): Wd (2048x2048) -> WdT bf16

__global__ __launch_bounds__(256) void prep(
    const float* __restrict__ hs, const float* __restrict__ Wq,
    const float* __restrict__ Wd, ushort_t* __restrict__ Xb,
    ushort_t* __restrict__ WqT, ushort_t* __restrict__ WdT) {
  __shared__ float t[64][65];
  int bx = blockIdx.x, tid = threadIdx.x;
  if (bx < 4096) {
    size_t i = ((size_t)bx * 256 + tid) * 8;
    float4 a = *(const float4*)(hs + i);
    float4 b = *(const float4*)(hs + i + 4);
    ushort4 o0; o0.x = f2bf(a.x); o0.y = f2bf(a.y); o0.z = f2bf(a.z); o0.w = f2bf(a.w);
    ushort4 o1; o1.x = f2bf(b.x); o1.y = f2bf(b.y); o1.z = f2bf(b.z); o1.w = f2bf(b.w);
    *(ushort4*)(Xb + i) = o0;
    *(ushort4*)(Xb + i + 4) = o1;
    return;
  }
  const float* in; ushort_t* out; int C, r0, c0;
  const int R = HID_;
  if (bx < 7168) {
    int tt = bx - 4096; C = N_QKV;
    c0 = (tt % 96) * 64; r0 = (tt / 96) * 64;
    in = Wq; out = WqT;
  } else {
    int tt = bx - 7168; C = HID_;
    c0 = (tt & 31) * 64; r0 = (tt >> 5) * 64;
    in = Wd; out = WdT;
  }
  int row = tid >> 4, col4 = (tid & 15) * 4;
#pragma unroll
  for (int i = 0; i < 4; ++i) {
    float4 v = *(const float4*)(in + (size_t)(r0 + row + i * 16) * C + c0 + col4);
    t[row + i * 16][col4 + 0] = v.x;
    t[row + i * 16][col4 + 1] = v.y;
    t[row + i * 16][col4 + 2] = v.z;
    t[row + i * 16][col4 + 3] = v.w;
  }
  __syncthreads();
#pragma unroll
  for (int i = 0; i < 4; ++i) {
    int cl = (tid >> 4) + i * 16;
    int r4 = (tid & 15) * 4;
    ushort4 o;
    o.x = f2bf(t[r4 + 0][cl]);
    o.y = f2bf(t[r4 + 1][cl]);
    o.z = f2bf(t[r4 + 2][cl]);
    o.w = f2bf(t[r4 + 3][cl]);
    *(ushort4*)(out + (size_t)(c0 + cl) * R + r0 + r4) = o;
  }
}

// ======= BK=64 XOR-swizzled GEMM core (staging + K-loop), 128x128 tile ======
// LDS tile: 128 rows x 64 cols bf16 = 16 KB, stored as 8 granules(16B)/row with
// phys granule p = r*8 + (g ^ (r&7)).  Staging lane l of chunk ch fetches
// row = ch*8 + (l>>3), logical granule (l&7)^(l>>3)  -> LDS slot ch*64+l.
// Fragment reads hit p%8 = g^(l16&7): 2-way bank aliasing (free).

#define GEMM_KLOOP(As, Bs, Ab, Bb, K)                                            \
  for (int kt = 0; kt < (K); kt += 64) {                                         \
    __syncthreads();                                                             \
    _Pragma("unroll")                                                            \
    for (int j = 0; j < 4; ++j) {                                                \
      int ch = wave * 4 + j;                                                     \
      gload16((Ab) + (size_t)(ch * 8 + lr) * (K) + kt + lg * 8, &(As)[ch * 512]);\
      gload16((Bb) + (size_t)(ch * 8 + lr) * (K) + kt + lg * 8, &(Bs)[ch * 512]);\
    }                                                                            \
    __syncthreads();                                                             \
    _Pragma("unroll")                                                            \
    for (int ks2 = 0; ks2 < 2; ++ks2) {                                          \
      bf16x8 af[4], bfr[4];                                                      \
      _Pragma("unroll")                                                          \
      for (int i = 0; i < 4; ++i) {                                              \
        int r = wm * 64 + i * 16 + l16;                                          \
        af[i] = *(const bf16x8*)&(As)[(r * 8 + ((ks2 * 4 + quad) ^ (r & 7))) * 8];\
      }                                                                          \
      _Pragma("unroll")                                                          \
      for (int j = 0; j < 4; ++j) {                                              \
        int r = wn * 64 + j * 16 + l16;                                          \
        bfr[j] = *(const bf16x8*)&(Bs)[(r * 8 + ((ks2 * 4 + quad) ^ (r & 7))) * 8];\
      }                                                                          \
      _Pragma("unroll")                                                          \
      for (int i = 0; i < 4; ++i)                                                \
        _Pragma("unroll")                                                        \
        for (int j = 0; j < 4; ++j)                                              \
          acc[i][j] = __builtin_amdgcn_mfma_f32_16x16x32_bf16(af[i], bfr[j],     \
                                                              acc[i][j], 0, 0, 0);\
    }                                                                            \
  }

// ================= 256x256 8-phase QKV GEMM (T2+T3+T4+T5) =================
// 512 threads = 8 waves (2M x 4N), per-wave output 128x64 (8 m-frags x 4 n-frags).
// LDS: A,B double-buffered 256x64 bf16 tiles = 128 KiB, same XOR-granule swizzle
// as the 128^2 core (verified 0 bank conflicts).
// Per K-step t (buf p=t&1), 4 phases, raw barriers (never vmcnt(0) in steady state):
//   P0: ds_read A0-3,B0-1      | MFMA quad (m0-3, n0-1)
//   P1: ds_read B2-3           | MFMA quad (m0-3, n2-3)
//   P2: ds_read A4-7, stage B(t+2)->Bs[p]   (B released after P1's 2nd barrier)
//                              | MFMA quad (m4-7, n2-3)
//   P3: stage A(t+2)->As[p]    (A released after P2's 2nd barrier)
//                              | MFMA quad (m4-7, n0-1); s_waitcnt vmcnt(8); barrier
// vmcnt(8): the 8 newest loads are tile t+2's; in-order retirement => tile t+1's
// 8 loads (issued one full K-step earlier) are complete. Epilogue fuses bias +
// rotary (Q/K) + V-transpose scatter; each wave's 64-col stripe sits in exactly
// one (head,part) 128-col slice.

__device__ __forceinline__ void stage4(const ushort_t* __restrict__ g,
                                       ushort_t* l, int wave, int lr, int lg,
                                       int K, int kt) {
#pragma unroll
  for (int j = 0; j < 4; ++j) {
    int ch = wave * 4 + j;
    gload16(g + (size_t)(ch * 8 + lr) * K + kt + lg * 8, l + ch * 512);
  }
}

#define LD_A(mg, Ap)                                                             \
  _Pragma("unroll")                                                              \
  for (int ii = 0; ii < 4; ++ii)                                                 \
    _Pragma("unroll")                                                            \
    for (int ks = 0; ks < 2; ++ks) {                                             \
      int r = wm * 128 + ((mg) * 4 + ii) * 16 + l16;                             \
      a[ii][ks] = *(const bf16x8*)&(Ap)[(r * 8 + ((ks * 4 + quad) ^ (r & 7))) * 8];\
    }

#define LD_B(ng, Bp, dst)                                                        \
  _Pragma("unroll")                                                              \
  for (int jj = 0; jj < 2; ++jj)                                                 \
    _Pragma("unroll")                                                            \
    for (int ks = 0; ks < 2; ++ks) {                                             \
      int r = wn * 64 + ((ng) * 2 + jj) * 16 + l16;                              \
      dst[jj][ks] = *(const bf16x8*)&(Bp)[(r * 8 + ((ks * 4 + quad) ^ (r & 7))) * 8];\
    }

#define PH_MFMA(mg, ng, bb)                                                      \
  _Pragma("unroll")                                                              \
  for (int ks = 0; ks < 2; ++ks)                                                 \
    _Pragma("unroll")                                                            \
    for (int ii = 0; ii < 4; ++ii)                                               \
      _Pragma("unroll")                                                          \
      for (int jj = 0; jj < 2; ++jj)                                             \
        acc[(mg) * 4 + ii][(ng) * 2 + jj] = __builtin_amdgcn_mfma_f32_16x16x32_bf16( \
            a[ii][ks], bb[jj][ks], acc[(mg) * 4 + ii][(ng) * 2 + jj], 0, 0, 0);

#define KSTEP(p, t)                                                              \
  {                                                                              \
    const ushort_t* Ap = &As[p][0];                                              \
    const ushort_t* Bp = &Bs[p][0];                                              \
    /* phase 0 */                                                                \
    LD_A(0, Ap)                                                                  \
    LD_B(0, Bp, b0)                                                              \
    barrier_raw();                                                               \
    asm volatile("s_waitcnt lgkmcnt(0)" ::: "memory");                           \
    __builtin_amdgcn_s_setprio(1);                                               \
    PH_MFMA(0, 0, b0)                                                            \
    __builtin_amdgcn_s_setprio(0);                                               \
    barrier_raw();                                                               \
    /* phase 1 */                                                                \
    LD_B(1, Bp, b1)                                                              \
    barrier_raw();                                                               \
    asm volatile("s_waitcnt lgkmcnt(0)" ::: "memory");                           \
    __builtin_amdgcn_s_setprio(1);                                               \
    PH_MFMA(0, 1, b1)                                                            \
    __builtin_amdgcn_s_setprio(0);                                               \
    barrier_raw();                                                               \
    /* phase 2: B LDS fully consumed -> stage B(t+2) into this buffer */         \
    LD_A(1, Ap)                                                                  \
    if ((t) + 2 < NT) stage4(Bb, &Bs[p][0], wave, lr, lg, K, ((t) + 2) * 64);    \
    barrier_raw();                                                               \
    asm volatile("s_waitcnt lgkmcnt(0)" ::: "memory");                           \
    __builtin_amdgcn_s_setprio(1);                                               \
    PH_MFMA(1, 1, b1)                                                            \
    __builtin_amdgcn_s_setprio(0);                                               \
    barrier_raw();                                                               \
    /* phase 3: A LDS fully consumed -> stage A(t+2) into this buffer */         \
    if ((t) + 2 < NT) stage4(Ab, &As[p][0], wave, lr, lg, K, ((t) + 2) * 64);    \
    barrier_raw();                                                               \
    __builtin_amdgcn_s_setprio(1);                                               \
    PH_MFMA(1, 0, b0)                                                            \
    __builtin_amdgcn_s_setprio(0);                                               \
    if ((t) + 2 < NT) { asm volatile("s_waitcnt vmcnt(8)" ::: "memory"); }       \
    else              { asm volatile("s_waitcnt vmcnt(0)" ::: "memory"); }       \
    barrier_raw();                                                               \
  }

__global__ __launch_bounds__(512, 2) void gemm_qkv2(
    const ushort_t* __restrict__ A, const ushort_t* __restrict__ Bt,
    const float* __restrict__ bias, const int* __restrict__ pids,
    ushort_t* __restrict__ Qb, ushort_t* __restrict__ Kb, ushort_t* __restrict__ Vt) {
  const int K = HID_;
  const int NT = HID_ / 64;  // 32 K-steps
  __shared__ alignas(16) ushort_t As[2][256 * 64];
  __shared__ alignas(16) ushort_t Bs[2][256 * 64];
  int tid = threadIdx.x;
  int wave = tid >> 6, lane = tid & 63;
  int quad = lane >> 4, l16 = lane & 15;
  int wm = wave >> 2, wn = wave & 3;
  int r0 = blockIdx.y * 256, c0 = blockIdx.x * 256;

  const ushort_t* Ab = A + (size_t)r0 * K;
  const ushort_t* Bb = Bt + (size_t)c0 * K;
  int lr = lane >> 3;               // row within 8-row chunk
  int lg = (lane & 7) ^ lr;         // swizzled logical granule

  f32x4 acc[8][4];
#pragma unroll
  for (int i = 0; i < 8; ++i)
#pragma unroll
    for (int j = 0; j < 4; ++j) acc[i][j] = (f32x4){0.f, 0.f, 0.f, 0.f};

  // prologue: stage K0 -> buf0, K1 -> buf1; wait K0 (8 newest = K1's stay in flight)
  stage4(Ab, &As[0][0], wave, lr, lg, K, 0);
  stage4(Bb, &Bs[0][0], wave, lr, lg, K, 0);
  stage4(Ab, &As[1][0], wave, lr, lg, K, 64);
  stage4(Bb, &Bs[1][0], wave, lr, lg, K, 64);
  asm volatile("s_waitcnt vmcnt(8)" ::: "memory");
  barrier_raw();

  bf16x8 a[4][2], b0[2][2], b1[2][2];
  for (int t2 = 0; t2 < NT; t2 += 2) {
    KSTEP(0, t2)
    KSTEP(1, t2 + 1)
  }

  // ---- epilogue: bias + rotary/scatter. Wave's 64-col stripe -> one (head,part).
  int hh = (c0 >> 7) + (wn >> 1);
  int part = hh % 3, head = hh / 3;
  float bv[4];
#pragma unroll
  for (int j = 0; j < 4; ++j) bv[j] = bias[c0 + wn * 64 + j * 16 + l16];

  if (part == 2) {
    // V: 4 consecutive s at same d -> transposed 8B stores
#pragma unroll
    for (int i = 0; i < 8; ++i) {
      int row = r0 + wm * 128 + i * 16 + quad * 4;
      int b = row >> 11, s = row & (S_ - 1);
#pragma unroll
      for (int j = 0; j < 4; ++j) {
        int d = (wn & 1) * 64 + j * 16 + l16;
        ushort4 pk;
        pk.x = f2bf(acc[i][j][0] + bv[j]);
        pk.y = f2bf(acc[i][j][1] + bv[j]);
        pk.z = f2bf(acc[i][j][2] + bv[j]);
        pk.w = f2bf(acc[i][j][3] + bv[j]);
        *(ushort4*)&Vt[((size_t)(b * H_ + head) * HS_ + d) * S_ + s] = pk;
      }
    }
  } else {
    ushort_t* Dst = (part == 0) ? Qb : Kb;
    float scale = (part == 0) ? SCALE_Q : 1.0f;
    float invf = __expf((float)l16 * (-9.210340371976184f / 16.0f)); // 10000^(-l16/16)
#pragma unroll
    for (int i = 0; i < 8; ++i) {
#pragma unroll
      for (int r = 0; r < 4; ++r) {
        int row = r0 + wm * 128 + i * 16 + quad * 4 + r;
        int b = row >> 11, s = row & (S_ - 1);
        size_t obase = ((size_t)(b * H_ + head) * S_ + s) * HS_ + (wn & 1) * 64;
        float vals[4];
#pragma unroll
        for (int j = 0; j < 4; ++j) vals[j] = acc[i][j][r] + bv[j];
        if ((wn & 1) == 0) {
          // rotary: d0 = l16 (j=0), d1 = 16+l16 (j=1); pass for j>=2
          int pos = pids[row];
          float sn, cs;
          sincosf((float)pos * invf, &sn, &cs);
          float v0 = vals[0], v1 = vals[1];
          vals[0] = v0 * cs - v1 * sn;
          vals[1] = v1 * cs + v0 * sn;
        }
#pragma unroll
        for (int j = 0; j < 4; ++j)
          Dst[obase + j * 16 + l16] = f2bf(vals[j] * scale);
      }
    }
  }
}

// ---------------- BK=64 swizzled bf16 GEMM: C = A(MxK) @ Bt(NxK)^T + bias ----------

template <int BF16OUT>
__global__ __launch_bounds__(256, 2) void gemm_bt(
    const ushort_t* __restrict__ A, const ushort_t* __restrict__ Bt,
    const float* __restrict__ bias, void* __restrict__ Cv,
    int M, int N, int K) {
  __shared__ alignas(16) ushort_t As[128 * 64];
  __shared__ alignas(16) ushort_t Bs[128 * 64];
  int tid = threadIdx.x;
  int wave = tid >> 6, lane = tid & 63;
  int quad = lane >> 4, l16 = lane & 15;
  int wm = wave >> 1, wn = wave & 1;
  int r0 = blockIdx.y * 128, c0 = blockIdx.x * 128;

  const ushort_t* Ab = A + (size_t)r0 * K;
  const ushort_t* Bb = Bt + (size_t)c0 * K;
  int lr = lane >> 3;
  int lg = (lane & 7) ^ lr;

  f32x4 acc[4][4];
#pragma unroll
  for (int i = 0; i < 4; ++i)
#pragma unroll
    for (int j = 0; j < 4; ++j) acc[i][j] = (f32x4){0.f, 0.f, 0.f, 0.f};

  GEMM_KLOOP(As, Bs, Ab, Bb, K)

  float* Cf = (float*)Cv;
  ushort_t* Chh = (ushort_t*)Cv;
#pragma unroll
  for (int i = 0; i < 4; ++i) {
    int row = r0 + wm * 64 + i * 16 + quad * 4;
#pragma unroll
    for (int j = 0; j < 4; ++j) {
      int col = c0 + wn * 64 + j * 16 + l16;
      float bvv = bias[col];
#pragma unroll
      for (int r = 0; r < 4; ++r) {
        float v = acc[i][j][r] + bvv;
        size_t idx = (size_t)(row + r) * N + col;
        if (BF16OUT) Chh[idx] = f2bf(v);
        else         Cf[idx] = v;
      }
    }
  }
}

// ---------------- flash attention (causal, online softmax, S^T layout) ----------------
// Q,K: (B,H,S,HS) bf16 (Q pre-scaled); Vt: (B,H,HS,S) bf16; out: (B,S,HID) bf16
// S^T = K Q^T so each lane owns ONE q-row (softmax: in-lane + 2 shuffles).
// PV as (PV)^T = V^T P^T. Double-buffered K/V, XOR-swizzled LDS (16B granules).
// Work-balanced q-tile permutation: co-resident blocks (consecutive x, or
// x stride with y+16) get q-indices summing to 15 -> equal CU workloads.

__global__ __launch_bounds__(256, 2) void flash_attn(
    const ushort_t* __restrict__ Q, const ushort_t* __restrict__ Kg,
    const ushort_t* __restrict__ Vt, const float* __restrict__ mask,
    ushort_t* __restrict__ Out) {
  __shared__ alignas(16) ushort_t Ks[2][64 * 128];
  __shared__ alignas(16) ushort_t Vs[2][128 * 64];
  __shared__ alignas(16) ushort_t Ps[4][32 * 64];  // per wave: P[q=32][n=64], swizzled

  int x = blockIdx.x, y = blockIdx.y;
  int qi = (x & 1) ? (x >> 1) : (15 - (x >> 1));   // consecutive-x pairs sum to 15
  if (y & 16) qi = 15 - qi;                        // stride-256 pairs also sum to 15
  int q0 = qi * 128;
  int bh = y;
  int b = bh >> 4, h = bh & 15;
  const ushort_t* Qh = Q + (size_t)bh * S_ * HS_;
  const ushort_t* Kh = Kg + (size_t)bh * S_ * HS_;
  const ushort_t* Vh = Vt + (size_t)bh * HS_ * S_;
  const float* mk = mask + (size_t)b * S_;

  int tid = threadIdx.x;
  int wave = tid >> 6, lane = tid & 63, quad = lane >> 4, l16 = lane & 15;

  bf16x8 qf[2][4];
#pragma unroll
  for (int i = 0; i < 2; ++i)
#pragma unroll
    for (int kb = 0; kb < 4; ++kb)
      qf[i][kb] = *(const bf16x8*)(
          Qh + (size_t)(q0 + wave * 32 + i * 16 + l16) * HS_ + kb * 32 + quad * 8);

  f32x4 o[2][8];
#pragma unroll
  for (int i = 0; i < 2; ++i)
#pragma unroll
    for (int dt = 0; dt < 8; ++dt) o[i][dt] = (f32x4){0.f, 0.f, 0.f, 0.f};
  float mrow[2] = {-1e30f, -1e30f};
  float lrow[2] = {0.f, 0.f};

  int ntiles = q0 / 64 + 2;

#pragma unroll
  for (int j = 0; j < 4; ++j) {
    int ch = wave * 4 + j;
    {
      int p = ch * 64 + lane;
      int r = p >> 4, g = (p & 15) ^ (r & 15);
      gload16(Kh + (size_t)r * HS_ + g * 8, &Ks[0][ch * 512]);
    }
    {
      int p = ch * 64 + lane;
      int r = p >> 3, g = (p & 7) ^ (r & 7);
      gload16(Vh + (size_t)r * S_ + g * 8, &Vs[0][ch * 512]);
    }
  }

  for (int it = 0; it < ntiles; ++it) {
    int bsel = it & 1;
    int n0 = it * 64;
    __syncthreads();

    if (it + 1 < ntiles) {
      int n1 = n0 + 64;
#pragma unroll
      for (int j = 0; j < 4; ++j) {
        int ch = wave * 4 + j;
        {
          int p = ch * 64 + lane;
          int r = p >> 4, g = (p & 15) ^ (r & 15);
          gload16(Kh + (size_t)(n1 + r) * HS_ + g * 8, &Ks[bsel ^ 1][ch * 512]);
        }
        {
          int p = ch * 64 + lane;
          int r = p >> 3, g = (p & 7) ^ (r & 7);
          gload16(Vh + (size_t)r * S_ + n1 + g * 8, &Vs[bsel ^ 1][ch * 512]);
        }
      }
    }

    float4 mkv[4];
#pragma unroll
    for (int t = 0; t < 4; ++t)
      mkv[t] = *(const float4*)&mk[n0 + t * 16 + quad * 4];
    bool edge = (it >= ntiles - 2);

    f32x4 s2[4][2];
#pragma unroll
    for (int t = 0; t < 4; ++t) {
      bf16x8 kf[4];
#pragma unroll
      for (int kb = 0; kb < 4; ++kb)
        kf[kb] = *(const bf16x8*)&Ks[bsel][(((t * 16 + l16) * 16) + ((kb * 4 + quad) ^ l16)) * 8];
#pragma unroll
      for (int i = 0; i < 2; ++i) {
        f32x4 a = (f32x4){0.f, 0.f, 0.f, 0.f};
#pragma unroll
        for (int kb = 0; kb < 4; ++kb)
          a = __builtin_amdgcn_mfma_f32_16x16x32_bf16(kf[kb], qf[i][kb], a, 0, 0, 0);
        s2[t][i] = a;
      }
    }

#pragma unroll
    for (int i = 0; i < 2; ++i) {
      int qg = q0 + wave * 32 + i * 16 + l16;
      float mx = -1e30f;
#pragma unroll
      for (int t = 0; t < 4; ++t)
#pragma unroll
        for (int reg = 0; reg < 4; ++reg) {
          float v = s2[t][i][reg] + mkv[t][reg];
          if (edge && (n0 + t * 16 + quad * 4 + reg > qg)) v = -1e30f;
          s2[t][i][reg] = v;
          mx = fmaxf(mx, v);
        }
      mx = fmaxf(mx, __shfl_xor(mx, 16, 64));
      mx = fmaxf(mx, __shfl_xor(mx, 32, 64));
      float mnew = fmaxf(mrow[i], mx);
      float alpha = __expf(mrow[i] - mnew);
      mrow[i] = mnew;
      float rs = 0.f;
#pragma unroll
      for (int t = 0; t < 4; ++t)
#pragma unroll
        for (int reg = 0; reg < 4; ++reg) {
          float p = __expf(s2[t][i][reg] - mnew);
          s2[t][i][reg] = p;
          rs += p;
        }
      rs += __shfl_xor(rs, 16, 64);
      rs += __shfl_xor(rs, 32, 64);
      lrow[i] = lrow[i] * alpha + rs;
#pragma unroll
      for (int dt = 0; dt < 8; ++dt) o[i][dt] *= alpha;

#pragma unroll
      for (int t = 0; t < 4; ++t) {
        ushort4 pk;
        pk.x = f2bf(s2[t][i][0]); pk.y = f2bf(s2[t][i][1]);
        pk.z = f2bf(s2[t][i][2]); pk.w = f2bf(s2[t][i][3]);
        *(ushort4*)((char*)&Ps[wave][0] + (i * 16 + l16) * 128 +
                    (((t * 2 + (quad >> 1)) ^ (l16 & 7)) * 16) + (quad & 1) * 8) = pk;
      }
    }
    __builtin_amdgcn_s_waitcnt(0xC07F);  // lgkmcnt(0)

    bf16x8 pf[2][2];
#pragma unroll
    for (int i = 0; i < 2; ++i)
#pragma unroll
      for (int kb = 0; kb < 2; ++kb)
        pf[i][kb] = *(const bf16x8*)((char*)&Ps[wave][0] + (i * 16 + l16) * 128 +
                                     (((kb * 4 + quad) ^ (l16 & 7)) * 16));
#pragma unroll
    for (int dt = 0; dt < 8; ++dt) {
#pragma unroll
      for (int kb = 0; kb < 2; ++kb) {
        bf16x8 vf = *(const bf16x8*)&Vs[bsel][((dt * 16 + l16) * 8 + ((kb * 4 + quad) ^ (l16 & 7))) * 8];
#pragma unroll
        for (int i = 0; i < 2; ++i)
          o[i][dt] = __builtin_amdgcn_mfma_f32_16x16x32_bf16(vf, pf[i][kb], o[i][dt], 0, 0, 0);
      }
    }
  }

  float invl[2] = {1.0f / lrow[0], 1.0f / lrow[1]};
#pragma unroll
  for (int i = 0; i < 2; ++i) {
    int qg = q0 + wave * 32 + i * 16 + l16;
#pragma unroll
    for (int dt = 0; dt < 8; ++dt) {
      ushort4 ov;
      ov.x = f2bf(o[i][dt][0] * invl[i]);
      ov.y = f2bf(o[i][dt][1] * invl[i]);
      ov.z = f2bf(o[i][dt][2] * invl[i]);
      ov.w = f2bf(o[i][dt][3] * invl[i]);
      *(ushort4*)&Out[((size_t)(b * S_ + qg)) * HID_ + h * HS_ + dt * 16 + quad * 4] = ov;
    }
  }
}

// ---------------- launcher ----------------

extern "C" void kernel_launch(void* const* d_in, const int* in_sizes, int n_in,
                              void* d_out, int out_size, void* d_ws, size_t ws_size,
                              hipStream_t stream) {
  const float* hs    = (const float*)d_in[0];
  const float* amask = (const float*)d_in[1];
  const int*   pids  = (const int*)d_in[2];
  const float* Wqkv  = (const float*)d_in[3];
  const float* bqkv  = (const float*)d_in[4];
  const float* Wd    = (const float*)d_in[5];
  const float* bd    = (const float*)d_in[6];
  float* out = (float*)d_out;

  // workspace layout (96 MB):
  //  [0,16M)   Xb (bf16 X) -> reused as attn after gemm_qkv
  //  [16,40M)  WqkvT   [40,48M) WdT
  //  [48,64M)  Qb      [64,80M)  Kb      [80,96M)  Vt
  char* ws = (char*)d_ws;
  ushort_t* Xb    = (ushort_t*)(ws);
  ushort_t* WqkvT = (ushort_t*)(ws + ((size_t)16 << 20));
  ushort_t* WdT   = (ushort_t*)(ws + ((size_t)40 << 20));
  ushort_t* Qb    = (ushort_t*)(ws + ((size_t)48 << 20));
  ushort_t* Kb    = (ushort_t*)(ws + ((size_t)64 << 20));
  ushort_t* Vt    = (ushort_t*)(ws + ((size_t)80 << 20));
  ushort_t* attn  = Xb;

  prep<<<8192, 256, 0, stream>>>(hs, Wqkv, Wd, Xb, WqkvT, WdT);
  gemm_qkv2<<<dim3(N_QKV / 256, (B_ * S_) / 256), 512, 0, stream>>>(
      Xb, WqkvT, bqkv, pids, Qb, Kb, Vt);
  flash_attn<<<dim3(S_ / 128, B_ * H_), 256, 0, stream>>>(Qb, Kb, Vt, amask, attn);
  gemm_bt<0><<<dim3(HID_ / 128, (B_ * S_) / 128), 256, 0, stream>>>(
      attn, WdT, bd, d_out, B_ * S_, HID_, HID_);
  (void)out; (void)in_sizes; (void)n_in; (void)out_size; (void)ws_size;
}

// Round 2
// 411.851 us; speedup vs baseline: 1.0056x; 1.0056x over previous
//
#include <hip/hip_runtime.h>

#define B_    2
#define S_    2048
#define H_    16
#define HS_   128
#define HID_  2048
#define N_QKV 6144
#define SCALE_Q 0.08838834764831845f  // 1/sqrt(128)

typedef unsigned short ushort_t;
typedef __attribute__((ext_vector_type(8))) __bf16 bf16x8;
typedef __attribute__((ext_vector_type(4))) float f32x4;

__device__ __forceinline__ float bf2f(ushort_t u) {
  union { unsigned int i; float f; } x; x.i = ((unsigned int)u) << 16; return x.f;
}
__device__ __forceinline__ ushort_t f2bf(float f) {
  union { float f; unsigned int i; } x; x.f = f;
  unsigned int u = x.i;
  u += 0x7fffu + ((u >> 16) & 1u);   // RNE
  return (ushort_t)(u >> 16);
}
// async global->LDS, 16B per lane; LDS dest = wave-uniform base + lane*16
__device__ __forceinline__ void gload16(const ushort_t* g, ushort_t* l) {
  __builtin_amdgcn_global_load_lds(
      (__attribute__((address_space(1))) void*)g,
      (__attribute__((address_space(3))) void*)l, 16, 0, 0);
}
// raw barrier with compiler memory fence on both sides (memory ops can't cross;
// register-only MFMA still can -> every MFMA cluster is additionally pinned with
// sched_barrier(0) per rule #18).
__device__ __forceinline__ void barrier_raw() {
  asm volatile("" ::: "memory");
  __builtin_amdgcn_s_barrier();
  asm volatile("" ::: "memory");
}

// ---------------- fused prep: X->bf16 conv + both weight transposes ----------------
__global__ __launch_bounds__(256) void prep(
    const float* __restrict__ hs, const float* __restrict__ Wq,
    const float* __restrict__ Wd, ushort_t* __restrict__ Xb,
    ushort_t* __restrict__ WqT, ushort_t* __restrict__ WdT) {
  __shared__ float t[64][65];
  int bx = blockIdx.x, tid = threadIdx.x;
  if (bx < 4096) {
    size_t i = ((size_t)bx * 256 + tid) * 8;
    float4 a = *(const float4*)(hs + i);
    float4 b = *(const float4*)(hs + i + 4);
    ushort4 o0; o0.x = f2bf(a.x); o0.y = f2bf(a.y); o0.z = f2bf(a.z); o0.w = f2bf(a.w);
    ushort4 o1; o1.x = f2bf(b.x); o1.y = f2bf(b.y); o1.z = f2bf(b.z); o1.w = f2bf(b.w);
    *(ushort4*)(Xb + i) = o0;
    *(ushort4*)(Xb + i + 4) = o1;
    return;
  }
  const float* in; ushort_t* out; int C, r0, c0;
  const int R = HID_;
  if (bx < 7168) {
    int tt = bx - 4096; C = N_QKV;
    c0 = (tt % 96) * 64; r0 = (tt / 96) * 64;
    in = Wq; out = WqT;
  } else {
    int tt = bx - 7168; C = HID_;
    c0 = (tt & 31) * 64; r0 = (tt >> 5) * 64;
    in = Wd; out = WdT;
  }
  int row = tid >> 4, col4 = (tid & 15) * 4;
#pragma unroll
  for (int i = 0; i < 4; ++i) {
    float4 v = *(const float4*)(in + (size_t)(r0 + row + i * 16) * C + c0 + col4);
    t[row + i * 16][col4 + 0] = v.x;
    t[row + i * 16][col4 + 1] = v.y;
    t[row + i * 16][col4 + 2] = v.z;
    t[row + i * 16][col4 + 3] = v.w;
  }
  __syncthreads();
#pragma unroll
  for (int i = 0; i < 4; ++i) {
    int cl = (tid >> 4) + i * 16;
    int r4 = (tid & 15) * 4;
    ushort4 o;
    o.x = f2bf(t[r4 + 0][cl]);
    o.y = f2bf(t[r4 + 1][cl]);
    o.z = f2bf(t[r4 + 2][cl]);
    o.w = f2bf(t[r4 + 3][cl]);
    *(ushort4*)(out + (size_t)(c0 + cl) * R + r0 + r4) = o;
  }
}

// ======= BK=64 XOR-swizzled GEMM core (staging + K-loop), 128x128 tile ======
// (used by gemm_bt for the dense projection)
#define GEMM_KLOOP(As, Bs, Ab, Bb, K)                                            \
  for (int kt = 0; kt < (K); kt += 64) {                                         \
    __syncthreads();                                                             \
    _Pragma("unroll")                                                            \
    for (int j = 0; j < 4; ++j) {                                                \
      int ch = wave * 4 + j;                                                     \
      gload16((Ab) + (size_t)(ch * 8 + lr) * (K) + kt + lg * 8, &(As)[ch * 512]);\
      gload16((Bb) + (size_t)(ch * 8 + lr) * (K) + kt + lg * 8, &(Bs)[ch * 512]);\
    }                                                                            \
    __syncthreads();                                                             \
    _Pragma("unroll")                                                            \
    for (int ks2 = 0; ks2 < 2; ++ks2) {                                          \
      bf16x8 af[4], bfr[4];                                                      \
      _Pragma("unroll")                                                          \
      for (int i = 0; i < 4; ++i) {                                              \
        int r = wm * 64 + i * 16 + l16;                                          \
        af[i] = *(const bf16x8*)&(As)[(r * 8 + ((ks2 * 4 + quad) ^ (r & 7))) * 8];\
      }                                                                          \
      _Pragma("unroll")                                                          \
      for (int j = 0; j < 4; ++j) {                                              \
        int r = wn * 64 + j * 16 + l16;                                          \
        bfr[j] = *(const bf16x8*)&(Bs)[(r * 8 + ((ks2 * 4 + quad) ^ (r & 7))) * 8];\
      }                                                                          \
      _Pragma("unroll")                                                          \
      for (int i = 0; i < 4; ++i)                                                \
        _Pragma("unroll")                                                        \
        for (int j = 0; j < 4; ++j)                                              \
          acc[i][j] = __builtin_amdgcn_mfma_f32_16x16x32_bf16(af[i], bfr[j],     \
                                                              acc[i][j], 0, 0, 0);\
    }                                                                            \
  }

// ================= 256x256 8-phase QKV GEMM (T1+T2+T3+T4+T5) =================
// Template-conformant port of the verified 256^2 8-phase schedule (m201):
//  - 512 thr = 8 waves (2M x 4N); per-wave C = 128x64 (8 m-frags x 4 n-frags).
//  - LDS 128 KiB: A,B double-buffered 256x64 tiles, XOR-granule swizzle
//    (0 bank conflicts, verified by counters in rounds 0-1).
//  - Per K-step s (buf p=s&1): 4 phases, each {ds_reads || stage 1 half-tile ->
//    barrier -> lgkmcnt(0) -> sched_barrier(0) -> setprio(1) -> 16 MFMA ->
//    setprio(0) -> sched_barrier(0) -> barrier}.  sched_barrier pins the MFMA
//    cluster in its phase (rule #18: register-only MFMA otherwise sinks across
//    raw barriers and collapses the interleave).
//  - Staging ledger: ph0/ph1 stage A-half0/1 of tile s+1 (buf q, released at
//    (s-1).ph2); ph2/ph3 stage B-half0/1 of tile s+2 (buf p, released at s.ph1).
//    Single counted s_waitcnt vmcnt(4) at ph3 (4 newest = B(s+2) halves; all
//    older incl. tile s+1 retired).  Never vmcnt(0) in steady state.
//  - XCD-chunked bijective block remap: each XCD gets 48 consecutive tiles =
//    2 full A-panel rows; per-K-step L2 working set ~2.8 MiB < 4 MiB.

__device__ __forceinline__ void stage_half(const ushort_t* __restrict__ g,
                                           ushort_t* l, int wave, int lr, int lg,
                                           int K, int kt, int half) {
#pragma unroll
  for (int j = 0; j < 2; ++j) {
    int ch = half * 16 + wave * 2 + j;   // 16 chunks of 8 rows per half-tile
    gload16(g + (size_t)(ch * 8 + lr) * K + kt + lg * 8, l + ch * 512);
  }
}

#define LD_A(mg, Ap)                                                             \
  _Pragma("unroll")                                                              \
  for (int ii = 0; ii < 4; ++ii)                                                 \
    _Pragma("unroll")                                                            \
    for (int ks = 0; ks < 2; ++ks) {                                             \
      int r = wm * 128 + ((mg) * 4 + ii) * 16 + l16;                             \
      a[ii][ks] = *(const bf16x8*)&(Ap)[(r * 8 + ((ks * 4 + quad) ^ (r & 7))) * 8];\
    }

#define LD_B(ng, Bp, dst)                                                        \
  _Pragma("unroll")                                                              \
  for (int jj = 0; jj < 2; ++jj)                                                 \
    _Pragma("unroll")                                                            \
    for (int ks = 0; ks < 2; ++ks) {                                             \
      int r = wn * 64 + ((ng) * 2 + jj) * 16 + l16;                              \
      dst[jj][ks] = *(const bf16x8*)&(Bp)[(r * 8 + ((ks * 4 + quad) ^ (r & 7))) * 8];\
    }

#define PH_MFMA(mg, ng, bb)                                                      \
  _Pragma("unroll")                                                              \
  for (int ks = 0; ks < 2; ++ks)                                                 \
    _Pragma("unroll")                                                            \
    for (int ii = 0; ii < 4; ++ii)                                               \
      _Pragma("unroll")                                                          \
      for (int jj = 0; jj < 2; ++jj)                                             \
        acc[(mg) * 4 + ii][(ng) * 2 + jj] = __builtin_amdgcn_mfma_f32_16x16x32_bf16( \
            a[ii][ks], bb[jj][ks], acc[(mg) * 4 + ii][(ng) * 2 + jj], 0, 0, 0);

#define MFMA_PHASE(mg, ng, bb)                                                   \
    __builtin_amdgcn_sched_barrier(0);                                           \
    __builtin_amdgcn_s_setprio(1);                                               \
    PH_MFMA(mg, ng, bb)                                                          \
    __builtin_amdgcn_s_setprio(0);                                               \
    __builtin_amdgcn_sched_barrier(0);

// p: buffer of tile s; q = p^1; kA = (s+1)*64; kB = (s+2)*64
// DOA/DOB: stage A(s+1)/B(s+2); DOV: emit vmcnt; VMN: vmcnt immediate
#define KSTEP(p, q, kA, kB, DOA, DOB, DOV, VMN)                                  \
  {                                                                              \
    const ushort_t* Ap = &As[p][0];                                              \
    const ushort_t* Bp = &Bs[p][0];                                              \
    /* phase 0 */                                                                \
    LD_A(0, Ap)                                                                  \
    LD_B(0, Bp, b0)                                                              \
    if (DOA) stage_half(Ab, &As[q][0], wave, lr, lg, K, (kA), 0);                \
    barrier_raw();                                                               \
    asm volatile("s_waitcnt lgkmcnt(0)" ::: "memory");                           \
    MFMA_PHASE(0, 0, b0)                                                         \
    barrier_raw();                                                               \
    /* phase 1 */                                                                \
    LD_B(1, Bp, b1)                                                              \
    if (DOA) stage_half(Ab, &As[q][0], wave, lr, lg, K, (kA), 1);                \
    barrier_raw();                                                               \
    asm volatile("s_waitcnt lgkmcnt(0)" ::: "memory");                           \
    MFMA_PHASE(0, 1, b1)                                                         \
    barrier_raw();                                                               \
    /* phase 2 (B of buf p released after ph1) */                                \
    LD_A(1, Ap)                                                                  \
    if (DOB) stage_half(Bb, &Bs[p][0], wave, lr, lg, K, (kB), 0);                \
    barrier_raw();                                                               \
    asm volatile("s_waitcnt lgkmcnt(0)" ::: "memory");                           \
    MFMA_PHASE(1, 1, b1)                                                         \
    barrier_raw();                                                               \
    /* phase 3 (no ds_reads; MFMA from live regs) */                             \
    if (DOB) stage_half(Bb, &Bs[p][0], wave, lr, lg, K, (kB), 1);                \
    barrier_raw();                                                               \
    MFMA_PHASE(1, 0, b0)                                                         \
    if (DOV) { asm volatile("s_waitcnt vmcnt(" #VMN ")" ::: "memory"); }         \
    barrier_raw();                                                               \
  }

__global__ __launch_bounds__(512, 2) void gemm_qkv2(
    const ushort_t* __restrict__ A, const ushort_t* __restrict__ Bt,
    const float* __restrict__ bias, const int* __restrict__ pids,
    ushort_t* __restrict__ Qb, ushort_t* __restrict__ Kb, ushort_t* __restrict__ Vt) {
  const int K = HID_;
  __shared__ alignas(16) ushort_t As[2][256 * 64];
  __shared__ alignas(16) ushort_t Bs[2][256 * 64];
  int tid = threadIdx.x;
  int wave = tid >> 6, lane = tid & 63;
  int quad = lane >> 4, l16 = lane & 15;
  int wm = wave >> 2, wn = wave & 3;

  // XCD-chunked bijective remap (grid 24x16 = 384 = 8 XCDs * 48)
  int bid = blockIdx.y * 24 + blockIdx.x;
  int nb = (bid & 7) * 48 + (bid >> 3);
  int r0 = (nb / 24) * 256, c0 = (nb % 24) * 256;

  const ushort_t* Ab = A + (size_t)r0 * K;
  const ushort_t* Bb = Bt + (size_t)c0 * K;
  int lr = lane >> 3;               // row within 8-row chunk
  int lg = (lane & 7) ^ lr;         // swizzled logical granule

  f32x4 acc[8][4];
#pragma unroll
  for (int i = 0; i < 8; ++i)
#pragma unroll
    for (int j = 0; j < 4; ++j) acc[i][j] = (f32x4){0.f, 0.f, 0.f, 0.f};

  // prologue: tile0 (A+B -> buf0), tile1 B -> buf1  (12 loads);
  // wait vmcnt(4): tile0's 8 loads done, B(1)'s 4 stay in flight.
  stage_half(Ab, &As[0][0], wave, lr, lg, K, 0, 0);
  stage_half(Ab, &As[0][0], wave, lr, lg, K, 0, 1);
  stage_half(Bb, &Bs[0][0], wave, lr, lg, K, 0, 0);
  stage_half(Bb, &Bs[0][0], wave, lr, lg, K, 0, 1);
  stage_half(Bb, &Bs[1][0], wave, lr, lg, K, 64, 0);
  stage_half(Bb, &Bs[1][0], wave, lr, lg, K, 64, 1);
  asm volatile("s_waitcnt vmcnt(4)" ::: "memory");
  barrier_raw();

  bf16x8 a[4][2], b0[2][2], b1[2][2];
  // steady state: s = 0..29 (tiles 2..31 staged here)
  for (int t2 = 0; t2 < 30; t2 += 2) {
    KSTEP(0, 1, (t2 + 1) * 64, (t2 + 2) * 64, 1, 1, 1, 4)
    KSTEP(1, 0, (t2 + 2) * 64, (t2 + 3) * 64, 1, 1, 1, 4)
  }
  // peel s=30: stage A(31) only; drain with vmcnt(0)
  KSTEP(0, 1, 31 * 64, 0, 1, 0, 1, 0)
  // peel s=31: pure compute
  KSTEP(1, 0, 0, 0, 0, 0, 0, 0)

  // ---- epilogue: bias + rotary/scatter. Wave's 64-col stripe -> one (head,part).
  int hh = (c0 >> 7) + (wn >> 1);
  int part = hh % 3, head = hh / 3;
  float bv[4];
#pragma unroll
  for (int j = 0; j < 4; ++j) bv[j] = bias[c0 + wn * 64 + j * 16 + l16];

  if (part == 2) {
    // V: 4 consecutive s at same d -> transposed 8B stores
#pragma unroll
    for (int i = 0; i < 8; ++i) {
      int row = r0 + wm * 128 + i * 16 + quad * 4;
      int b = row >> 11, s = row & (S_ - 1);
#pragma unroll
      for (int j = 0; j < 4; ++j) {
        int d = (wn & 1) * 64 + j * 16 + l16;
        ushort4 pk;
        pk.x = f2bf(acc[i][j][0] + bv[j]);
        pk.y = f2bf(acc[i][j][1] + bv[j]);
        pk.z = f2bf(acc[i][j][2] + bv[j]);
        pk.w = f2bf(acc[i][j][3] + bv[j]);
        *(ushort4*)&Vt[((size_t)(b * H_ + head) * HS_ + d) * S_ + s] = pk;
      }
    }
  } else {
    ushort_t* Dst = (part == 0) ? Qb : Kb;
    float scale = (part == 0) ? SCALE_Q : 1.0f;
    float invf = __expf((float)l16 * (-9.210340371976184f / 16.0f)); // 10000^(-l16/16)
#pragma unroll
    for (int i = 0; i < 8; ++i) {
#pragma unroll
      for (int r = 0; r < 4; ++r) {
        int row = r0 + wm * 128 + i * 16 + quad * 4 + r;
        int b = row >> 11, s = row & (S_ - 1);
        size_t obase = ((size_t)(b * H_ + head) * S_ + s) * HS_ + (wn & 1) * 64;
        float vals[4];
#pragma unroll
        for (int j = 0; j < 4; ++j) vals[j] = acc[i][j][r] + bv[j];
        if ((wn & 1) == 0) {
          // rotary: d0 = l16 (j=0), d1 = 16+l16 (j=1); pass for j>=2
          int pos = pids[row];
          float sn, cs;
          sincosf((float)pos * invf, &sn, &cs);
          float v0 = vals[0], v1 = vals[1];
          vals[0] = v0 * cs - v1 * sn;
          vals[1] = v1 * cs + v0 * sn;
        }
#pragma unroll
        for (int j = 0; j < 4; ++j)
          Dst[obase + j * 16 + l16] = f2bf(vals[j] * scale);
      }
    }
  }
}

// ---------------- BK=64 swizzled bf16 GEMM: C = A(MxK) @ Bt(NxK)^T + bias ----------

template <int BF16OUT>
__global__ __launch_bounds__(256, 2) void gemm_bt(
    const ushort_t* __restrict__ A, const ushort_t* __restrict__ Bt,
    const float* __restrict__ bias, void* __restrict__ Cv,
    int M, int N, int K) {
  __shared__ alignas(16) ushort_t As[128 * 64];
  __shared__ alignas(16) ushort_t Bs[128 * 64];
  int tid = threadIdx.x;
  int wave = tid >> 6, lane = tid & 63;
  int quad = lane >> 4, l16 = lane & 15;
  int wm = wave >> 1, wn = wave & 1;
  int r0 = blockIdx.y * 128, c0 = blockIdx.x * 128;

  const ushort_t* Ab = A + (size_t)r0 * K;
  const ushort_t* Bb = Bt + (size_t)c0 * K;
  int lr = lane >> 3;
  int lg = (lane & 7) ^ lr;

  f32x4 acc[4][4];
#pragma unroll
  for (int i = 0; i < 4; ++i)
#pragma unroll
    for (int j = 0; j < 4; ++j) acc[i][j] = (f32x4){0.f, 0.f, 0.f, 0.f};

  GEMM_KLOOP(As, Bs, Ab, Bb, K)

  float* Cf = (float*)Cv;
  ushort_t* Chh = (ushort_t*)Cv;
#pragma unroll
  for (int i = 0; i < 4; ++i) {
    int row = r0 + wm * 64 + i * 16 + quad * 4;
#pragma unroll
    for (int j = 0; j < 4; ++j) {
      int col = c0 + wn * 64 + j * 16 + l16;
      float bvv = bias[col];
#pragma unroll
      for (int r = 0; r < 4; ++r) {
        float v = acc[i][j][r] + bvv;
        size_t idx = (size_t)(row + r) * N + col;
        if (BF16OUT) Chh[idx] = f2bf(v);
        else         Cf[idx] = v;
      }
    }
  }
}

// ---------------- flash attention (causal, online softmax, S^T layout) ----------------
// Q,K: (B,H,S,HS) bf16 (Q pre-scaled); Vt: (B,H,HS,S) bf16; out: (B,S,HID) bf16
// S^T = K Q^T so each lane owns ONE q-row (softmax: in-lane + 2 shuffles).
// PV as (PV)^T = V^T P^T. Double-buffered K/V, XOR-swizzled LDS (16B granules).
// T5: setprio(1) around MFMA clusters (waves of the 2 co-resident blocks are at
// different phases -> scheduler can favor MFMA-entering waves; m191 +4-7%).

__global__ __launch_bounds__(256, 2) void flash_attn(
    const ushort_t* __restrict__ Q, const ushort_t* __restrict__ Kg,
    const ushort_t* __restrict__ Vt, const float* __restrict__ mask,
    ushort_t* __restrict__ Out) {
  __shared__ alignas(16) ushort_t Ks[2][64 * 128];
  __shared__ alignas(16) ushort_t Vs[2][128 * 64];
  __shared__ alignas(16) ushort_t Ps[4][32 * 64];  // per wave: P[q=32][n=64], swizzled

  int x = blockIdx.x, y = blockIdx.y;
  int qi = (x & 1) ? (x >> 1) : (15 - (x >> 1));   // consecutive-x pairs sum to 15
  if (y & 16) qi = 15 - qi;                        // stride-256 pairs also sum to 15
  int q0 = qi * 128;
  int bh = y;
  int b = bh >> 4, h = bh & 15;
  const ushort_t* Qh = Q + (size_t)bh * S_ * HS_;
  const ushort_t* Kh = Kg + (size_t)bh * S_ * HS_;
  const ushort_t* Vh = Vt + (size_t)bh * HS_ * S_;
  const float* mk = mask + (size_t)b * S_;

  int tid = threadIdx.x;
  int wave = tid >> 6, lane = tid & 63, quad = lane >> 4, l16 = lane & 15;

  bf16x8 qf[2][4];
#pragma unroll
  for (int i = 0; i < 2; ++i)
#pragma unroll
    for (int kb = 0; kb < 4; ++kb)
      qf[i][kb] = *(const bf16x8*)(
          Qh + (size_t)(q0 + wave * 32 + i * 16 + l16) * HS_ + kb * 32 + quad * 8);

  f32x4 o[2][8];
#pragma unroll
  for (int i = 0; i < 2; ++i)
#pragma unroll
    for (int dt = 0; dt < 8; ++dt) o[i][dt] = (f32x4){0.f, 0.f, 0.f, 0.f};
  float mrow[2] = {-1e30f, -1e30f};
  float lrow[2] = {0.f, 0.f};

  int ntiles = q0 / 64 + 2;

#pragma unroll
  for (int j = 0; j < 4; ++j) {
    int ch = wave * 4 + j;
    {
      int p = ch * 64 + lane;
      int r = p >> 4, g = (p & 15) ^ (r & 15);
      gload16(Kh + (size_t)r * HS_ + g * 8, &Ks[0][ch * 512]);
    }
    {
      int p = ch * 64 + lane;
      int r = p >> 3, g = (p & 7) ^ (r & 7);
      gload16(Vh + (size_t)r * S_ + g * 8, &Vs[0][ch * 512]);
    }
  }

  for (int it = 0; it < ntiles; ++it) {
    int bsel = it & 1;
    int n0 = it * 64;
    __syncthreads();

    if (it + 1 < ntiles) {
      int n1 = n0 + 64;
#pragma unroll
      for (int j = 0; j < 4; ++j) {
        int ch = wave * 4 + j;
        {
          int p = ch * 64 + lane;
          int r = p >> 4, g = (p & 15) ^ (r & 15);
          gload16(Kh + (size_t)(n1 + r) * HS_ + g * 8, &Ks[bsel ^ 1][ch * 512]);
        }
        {
          int p = ch * 64 + lane;
          int r = p >> 3, g = (p & 7) ^ (r & 7);
          gload16(Vh + (size_t)r * S_ + n1 + g * 8, &Vs[bsel ^ 1][ch * 512]);
        }
      }
    }

    float4 mkv[4];
#pragma unroll
    for (int t = 0; t < 4; ++t)
      mkv[t] = *(const float4*)&mk[n0 + t * 16 + quad * 4];
    bool edge = (it >= ntiles - 2);

    f32x4 s2[4][2];
#pragma unroll
    for (int t = 0; t < 4; ++t) {
      bf16x8 kf[4];
#pragma unroll
      for (int kb = 0; kb < 4; ++kb)
        kf[kb] = *(const bf16x8*)&Ks[bsel][(((t * 16 + l16) * 16) + ((kb * 4 + quad) ^ l16)) * 8];
      __builtin_amdgcn_s_setprio(1);
#pragma unroll
      for (int i = 0; i < 2; ++i) {
        f32x4 a = (f32x4){0.f, 0.f, 0.f, 0.f};
#pragma unroll
        for (int kb = 0; kb < 4; ++kb)
          a = __builtin_amdgcn_mfma_f32_16x16x32_bf16(kf[kb], qf[i][kb], a, 0, 0, 0);
        s2[t][i] = a;
      }
      __builtin_amdgcn_s_setprio(0);
    }

#pragma unroll
    for (int i = 0; i < 2; ++i) {
      int qg = q0 + wave * 32 + i * 16 + l16;
      float mx = -1e30f;
#pragma unroll
      for (int t = 0; t < 4; ++t)
#pragma unroll
        for (int reg = 0; reg < 4; ++reg) {
          float v = s2[t][i][reg] + mkv[t][reg];
          if (edge && (n0 + t * 16 + quad * 4 + reg > qg)) v = -1e30f;
          s2[t][i][reg] = v;
          mx = fmaxf(mx, v);
        }
      mx = fmaxf(mx, __shfl_xor(mx, 16, 64));
      mx = fmaxf(mx, __shfl_xor(mx, 32, 64));
      float mnew = fmaxf(mrow[i], mx);
      float alpha = __expf(mrow[i] - mnew);
      mrow[i] = mnew;
      float rs = 0.f;
#pragma unroll
      for (int t = 0; t < 4; ++t)
#pragma unroll
        for (int reg = 0; reg < 4; ++reg) {
          float p = __expf(s2[t][i][reg] - mnew);
          s2[t][i][reg] = p;
          rs += p;
        }
      rs += __shfl_xor(rs, 16, 64);
      rs += __shfl_xor(rs, 32, 64);
      lrow[i] = lrow[i] * alpha + rs;
#pragma unroll
      for (int dt = 0; dt < 8; ++dt) o[i][dt] *= alpha;

#pragma unroll
      for (int t = 0; t < 4; ++t) {
        ushort4 pk;
        pk.x = f2bf(s2[t][i][0]); pk.y = f2bf(s2[t][i][1]);
        pk.z = f2bf(s2[t][i][2]); pk.w = f2bf(s2[t][i][3]);
        *(ushort4*)((char*)&Ps[wave][0] + (i * 16 + l16) * 128 +
                    (((t * 2 + (quad >> 1)) ^ (l16 & 7)) * 16) + (quad & 1) * 8) = pk;
      }
    }
    __builtin_amdgcn_s_waitcnt(0xC07F);  // lgkmcnt(0)

    bf16x8 pf[2][2];
#pragma unroll
    for (int i = 0; i < 2; ++i)
#pragma unroll
      for (int kb = 0; kb < 2; ++kb)
        pf[i][kb] = *(const bf16x8*)((char*)&Ps[wave][0] + (i * 16 + l16) * 128 +
                                     (((kb * 4 + quad) ^ (l16 & 7)) * 16));
    __builtin_amdgcn_s_setprio(1);
#pragma unroll
    for (int dt = 0; dt < 8; ++dt) {
#pragma unroll
      for (int kb = 0; kb < 2; ++kb) {
        bf16x8 vf = *(const bf16x8*)&Vs[bsel][((dt * 16 + l16) * 8 + ((kb * 4 + quad) ^ (l16 & 7))) * 8];
#pragma unroll
        for (int i = 0; i < 2; ++i)
          o[i][dt] = __builtin_amdgcn_mfma_f32_16x16x32_bf16(vf, pf[i][kb], o[i][dt], 0, 0, 0);
      }
    }
    __builtin_amdgcn_s_setprio(0);
  }

  float invl[2] = {1.0f / lrow[0], 1.0f / lrow[1]};
#pragma unroll
  for (int i = 0; i < 2; ++i) {
    int qg = q0 + wave * 32 + i * 16 + l16;
#pragma unroll
    for (int dt = 0; dt < 8; ++dt) {
      ushort4 ov;
      ov.x = f2bf(o[i][dt][0] * invl[i]);
      ov.y = f2bf(o[i][dt][1] * invl[i]);
      ov.z = f2bf(o[i][dt][2] * invl[i]);
      ov.w = f2bf(o[i][dt][3] * invl[i]);
      *(ushort4*)&Out[((size_t)(b * S_ + qg)) * HID_ + h * HS_ + dt * 16 + quad * 4] = ov;
    }
  }
}

// ---------------- launcher ----------------

extern "C" void kernel_launch(void* const* d_in, const int* in_sizes, int n_in,
                              void* d_out, int out_size, void* d_ws, size_t ws_size,
                              hipStream_t stream) {
  const float* hs    = (const float*)d_in[0];
  const float* amask = (const float*)d_in[1];
  const int*   pids  = (const int*)d_in[2];
  const float* Wqkv  = (const float*)d_in[3];
  const float* bqkv  = (const float*)d_in[4];
  const float* Wd    = (const float*)d_in[5];
  const float* bd    = (const float*)d_in[6];
  float* out = (float*)d_out;

  // workspace layout (96 MB):
  //  [0,16M)   Xb (bf16 X) -> reused as attn after gemm_qkv
  //  [16,40M)  WqkvT   [40,48M) WdT
  //  [48,64M)  Qb      [64,80M)  Kb      [80,96M)  Vt
  char* ws = (char*)d_ws;
  ushort_t* Xb    = (ushort_t*)(ws);
  ushort_t* WqkvT = (ushort_t*)(ws + ((size_t)16 << 20));
  ushort_t* WdT   = (ushort_t*)(ws + ((size_t)40 << 20));
  ushort_t* Qb    = (ushort_t*)(ws + ((size_t)48 << 20));
  ushort_t* Kb    = (ushort_t*)(ws + ((size_t)64 << 20));
  ushort_t* Vt    = (ushort_t*)(ws + ((size_t)80 << 20));
  ushort_t* attn  = Xb;

  prep<<<8192, 256, 0, stream>>>(hs, Wqkv, Wd, Xb, WqkvT, WdT);
  gemm_qkv2<<<dim3(N_QKV / 256, (B_ * S_) / 256), 512, 0, stream>>>(
      Xb, WqkvT, bqkv, pids, Qb, Kb, Vt);
  flash_attn<<<dim3(S_ / 128, B_ * H_), 256, 0, stream>>>(Qb, Kb, Vt, amask, attn);
  gemm_bt<0><<<dim3(HID_ / 128, (B_ * S_) / 128), 256, 0, stream>>>(
      attn, WdT, bd, d_out, B_ * S_, HID_, HID_);
  (void)out; (void)in_sizes; (void)n_in; (void)out_size; (void)ws_size;
}

// Round 3
// 381.762 us; speedup vs baseline: 1.0848x; 1.0788x over previous
//
#include <hip/hip_runtime.h>

#define B_    2
#define S_    2048
#define H_    16
#define HS_   128
#define HID_  2048
#define N_QKV 6144
#define SCALE_Q 0.08838834764831845f  // 1/sqrt(128)

typedef unsigned short ushort_t;
typedef __attribute__((ext_vector_type(8))) __bf16 bf16x8;
typedef __attribute__((ext_vector_type(4))) float f32x4;

__device__ __forceinline__ float bf2f(ushort_t u) {
  union { unsigned int i; float f; } x; x.i = ((unsigned int)u) << 16; return x.f;
}
__device__ __forceinline__ ushort_t f2bf(float f) {
  union { float f; unsigned int i; } x; x.f = f;
  unsigned int u = x.i;
  u += 0x7fffu + ((u >> 16) & 1u);   // RNE
  return (ushort_t)(u >> 16);
}
// async global->LDS, 16B per lane; LDS dest = wave-uniform base + lane*16
__device__ __forceinline__ void gload16(const ushort_t* g, ushort_t* l) {
  __builtin_amdgcn_global_load_lds(
      (__attribute__((address_space(1))) void*)g,
      (__attribute__((address_space(3))) void*)l, 16, 0, 0);
}

// ---------------- fused prep: X->bf16 conv + both weight transposes ----------------
// blocks [0,4096): conv (8 floats/thread)
// blocks [4096,7168): Wqkv (2048x6144) -> WqkvT (6144x2048) bf16, 64x64 tiles
// blocks [7168,8192): Wd (2048x2048) -> WdT bf16

__global__ __launch_bounds__(256) void prep(
    const float* __restrict__ hs, const float* __restrict__ Wq,
    const float* __restrict__ Wd, ushort_t* __restrict__ Xb,
    ushort_t* __restrict__ WqT, ushort_t* __restrict__ WdT) {
  __shared__ float t[64][65];
  int bx = blockIdx.x, tid = threadIdx.x;
  if (bx < 4096) {
    size_t i = ((size_t)bx * 256 + tid) * 8;
    float4 a = *(const float4*)(hs + i);
    float4 b = *(const float4*)(hs + i + 4);
    ushort4 o0; o0.x = f2bf(a.x); o0.y = f2bf(a.y); o0.z = f2bf(a.z); o0.w = f2bf(a.w);
    ushort4 o1; o1.x = f2bf(b.x); o1.y = f2bf(b.y); o1.z = f2bf(b.z); o1.w = f2bf(b.w);
    *(ushort4*)(Xb + i) = o0;
    *(ushort4*)(Xb + i + 4) = o1;
    return;
  }
  const float* in; ushort_t* out; int C, r0, c0;
  const int R = HID_;
  if (bx < 7168) {
    int tt = bx - 4096; C = N_QKV;
    c0 = (tt % 96) * 64; r0 = (tt / 96) * 64;
    in = Wq; out = WqT;
  } else {
    int tt = bx - 7168; C = HID_;
    c0 = (tt & 31) * 64; r0 = (tt >> 5) * 64;
    in = Wd; out = WdT;
  }
  int row = tid >> 4, col4 = (tid & 15) * 4;
#pragma unroll
  for (int i = 0; i < 4; ++i) {
    float4 v = *(const float4*)(in + (size_t)(r0 + row + i * 16) * C + c0 + col4);
    t[row + i * 16][col4 + 0] = v.x;
    t[row + i * 16][col4 + 1] = v.y;
    t[row + i * 16][col4 + 2] = v.z;
    t[row + i * 16][col4 + 3] = v.w;
  }
  __syncthreads();
#pragma unroll
  for (int i = 0; i < 4; ++i) {
    int cl = (tid >> 4) + i * 16;
    int r4 = (tid & 15) * 4;
    ushort4 o;
    o.x = f2bf(t[r4 + 0][cl]);
    o.y = f2bf(t[r4 + 1][cl]);
    o.z = f2bf(t[r4 + 2][cl]);
    o.w = f2bf(t[r4 + 3][cl]);
    *(ushort4*)(out + (size_t)(c0 + cl) * R + r0 + r4) = o;
  }
}

// ======= BK=64 XOR-swizzled GEMM core (staging + K-loop), shared by both GEMMs ======
// LDS tile: 128 rows x 64 cols bf16 = 16 KB, stored as 8 granules(16B)/row with
// phys granule p = r*8 + (g ^ (r&7)).  Staging lane l of chunk ch fetches
// row = ch*8 + (l>>3), logical granule (l&7)^(l>>3)  -> LDS slot ch*64+l.
// Fragment reads hit p%8 = g^(l16&7): 2-way bank aliasing (free).

#define GEMM_KLOOP(As, Bs, Ab, Bb, K)                                            \
  for (int kt = 0; kt < (K); kt += 64) {                                         \
    __syncthreads();                                                             \
    _Pragma("unroll")                                                            \
    for (int j = 0; j < 4; ++j) {                                                \
      int ch = wave * 4 + j;                                                     \
      gload16((Ab) + (size_t)(ch * 8 + lr) * (K) + kt + lg * 8, &(As)[ch * 512]);\
      gload16((Bb) + (size_t)(ch * 8 + lr) * (K) + kt + lg * 8, &(Bs)[ch * 512]);\
    }                                                                            \
    __syncthreads();                                                             \
    _Pragma("unroll")                                                            \
    for (int ks2 = 0; ks2 < 2; ++ks2) {                                          \
      bf16x8 af[4], bfr[4];                                                      \
      _Pragma("unroll")                                                          \
      for (int i = 0; i < 4; ++i) {                                              \
        int r = wm * 64 + i * 16 + l16;                                          \
        af[i] = *(const bf16x8*)&(As)[(r * 8 + ((ks2 * 4 + quad) ^ (r & 7))) * 8];\
      }                                                                          \
      _Pragma("unroll")                                                          \
      for (int j = 0; j < 4; ++j) {                                              \
        int r = wn * 64 + j * 16 + l16;                                          \
        bfr[j] = *(const bf16x8*)&(Bs)[(r * 8 + ((ks2 * 4 + quad) ^ (r & 7))) * 8];\
      }                                                                          \
      _Pragma("unroll")                                                          \
      for (int i = 0; i < 4; ++i)                                                \
        _Pragma("unroll")                                                        \
        for (int j = 0; j < 4; ++j)                                              \
          acc[i][j] = __builtin_amdgcn_mfma_f32_16x16x32_bf16(af[i], bfr[j],     \
                                                              acc[i][j], 0, 0, 0);\
    }                                                                            \
  }

// ---------------- fused QKV GEMM: X(4096x2048) @ WqkvT^T + rotary + scatter ----------
// Each 128-col tile == one (head, part) slice: part 0 -> Qb(b,h,s,d) w/ rotary+scale,
// part 1 -> Kb(b,h,s,d) w/ rotary, part 2 -> Vt(b,h,d,s) transposed (8B stores).

__global__ __launch_bounds__(256, 2) void gemm_qkv(
    const ushort_t* __restrict__ A, const ushort_t* __restrict__ Bt,
    const float* __restrict__ bias, const int* __restrict__ pids,
    ushort_t* __restrict__ Qb, ushort_t* __restrict__ Kb, ushort_t* __restrict__ Vt) {
  const int K = HID_;
  __shared__ alignas(16) ushort_t As[128 * 64];
  __shared__ alignas(16) ushort_t Bs[128 * 64];
  int tid = threadIdx.x;
  int wave = tid >> 6, lane = tid & 63;
  int quad = lane >> 4, l16 = lane & 15;
  int wm = wave >> 1, wn = wave & 1;
  int r0 = blockIdx.y * 128, c0 = blockIdx.x * 128;

  const ushort_t* Ab = A + (size_t)r0 * K;
  const ushort_t* Bb = Bt + (size_t)c0 * K;
  int lr = lane >> 3;               // row within 8-row chunk
  int lg = (lane & 7) ^ lr;         // swizzled logical granule

  f32x4 acc[4][4];
#pragma unroll
  for (int i = 0; i < 4; ++i)
#pragma unroll
    for (int j = 0; j < 4; ++j) acc[i][j] = (f32x4){0.f, 0.f, 0.f, 0.f};

  GEMM_KLOOP(As, Bs, Ab, Bb, K)

  int hh = blockIdx.x / 3, part = blockIdx.x % 3;
  float bv[4];
#pragma unroll
  for (int j = 0; j < 4; ++j) bv[j] = bias[c0 + wn * 64 + j * 16 + l16];

  if (part == 2) {
    // V: row chunk = 4 consecutive s at same d -> transposed 8B stores
#pragma unroll
    for (int i = 0; i < 4; ++i) {
      int row = r0 + wm * 64 + i * 16 + quad * 4;
      int b = row >> 11, s = row & (S_ - 1);
#pragma unroll
      for (int j = 0; j < 4; ++j) {
        int d = wn * 64 + j * 16 + l16;
        ushort4 pk;
        pk.x = f2bf(acc[i][j][0] + bv[j]);
        pk.y = f2bf(acc[i][j][1] + bv[j]);
        pk.z = f2bf(acc[i][j][2] + bv[j]);
        pk.w = f2bf(acc[i][j][3] + bv[j]);
        *(ushort4*)&Vt[((size_t)(b * H_ + hh) * HS_ + d) * S_ + s] = pk;
      }
    }
  } else {
    ushort_t* Dst = (part == 0) ? Qb : Kb;
    float scale = (part == 0) ? SCALE_Q : 1.0f;
    float invf = __expf((float)l16 * (-9.210340371976184f / 16.0f)); // 10000^(-l16/16)
#pragma unroll
    for (int i = 0; i < 4; ++i) {
#pragma unroll
      for (int r = 0; r < 4; ++r) {
        int row = r0 + wm * 64 + i * 16 + quad * 4 + r;
        int b = row >> 11, s = row & (S_ - 1);
        size_t obase = ((size_t)(b * H_ + hh) * S_ + s) * HS_ + wn * 64;
        float vals[4];
#pragma unroll
        for (int j = 0; j < 4; ++j) vals[j] = acc[i][j][r] + bv[j];
        if (wn == 0) {
          // rotary: d0 = l16 (j=0), d1 = 16+l16 (j=1); pass for j>=2
          int pos = pids[row];
          float sn, cs;
          sincosf((float)pos * invf, &sn, &cs);
          float v0 = vals[0], v1 = vals[1];
          vals[0] = v0 * cs - v1 * sn;
          vals[1] = v1 * cs + v0 * sn;
        }
#pragma unroll
        for (int j = 0; j < 4; ++j)
          Dst[obase + j * 16 + l16] = f2bf(vals[j] * scale);
      }
    }
  }
}

// ---------------- BK=64 swizzled bf16 GEMM: C = A(MxK) @ Bt(NxK)^T + bias ----------

template <int BF16OUT>
__global__ __launch_bounds__(256, 2) void gemm_bt(
    const ushort_t* __restrict__ A, const ushort_t* __restrict__ Bt,
    const float* __restrict__ bias, void* __restrict__ Cv,
    int M, int N, int K) {
  __shared__ alignas(16) ushort_t As[128 * 64];
  __shared__ alignas(16) ushort_t Bs[128 * 64];
  int tid = threadIdx.x;
  int wave = tid >> 6, lane = tid & 63;
  int quad = lane >> 4, l16 = lane & 15;
  int wm = wave >> 1, wn = wave & 1;
  int r0 = blockIdx.y * 128, c0 = blockIdx.x * 128;

  const ushort_t* Ab = A + (size_t)r0 * K;
  const ushort_t* Bb = Bt + (size_t)c0 * K;
  int lr = lane >> 3;
  int lg = (lane & 7) ^ lr;

  f32x4 acc[4][4];
#pragma unroll
  for (int i = 0; i < 4; ++i)
#pragma unroll
    for (int j = 0; j < 4; ++j) acc[i][j] = (f32x4){0.f, 0.f, 0.f, 0.f};

  GEMM_KLOOP(As, Bs, Ab, Bb, K)

  float* Cf = (float*)Cv;
  ushort_t* Chh = (ushort_t*)Cv;
#pragma unroll
  for (int i = 0; i < 4; ++i) {
    int row = r0 + wm * 64 + i * 16 + quad * 4;
#pragma unroll
    for (int j = 0; j < 4; ++j) {
      int col = c0 + wn * 64 + j * 16 + l16;
      float bvv = bias[col];
#pragma unroll
      for (int r = 0; r < 4; ++r) {
        float v = acc[i][j][r] + bvv;
        size_t idx = (size_t)(row + r) * N + col;
        if (BF16OUT) Chh[idx] = f2bf(v);
        else         Cf[idx] = v;
      }
    }
  }
}

// ---------------- flash attention (causal, online softmax, S^T layout) ----------------
// Q,K: (B,H,S,HS) bf16 (Q pre-scaled); Vt: (B,H,HS,S) bf16; out: (B,S,HID) bf16
// S^T = K Q^T so each lane owns ONE q-row (softmax: in-lane + 2 shuffles).
// PV as (PV)^T = V^T P^T. Double-buffered K/V, XOR-swizzled LDS (16B granules).
// T5 setprio around MFMA clusters (m191: +4-7% attn).
// T13 defer-max (THR=8): skip O-rescale when the whole wave's row-max growth <= 8
// (m214v23/m239: +5%); P bounded by e^8, f32 accum, wave-uniform branch.

__global__ __launch_bounds__(256, 2) void flash_attn(
    const ushort_t* __restrict__ Q, const ushort_t* __restrict__ Kg,
    const ushort_t* __restrict__ Vt, const float* __restrict__ mask,
    ushort_t* __restrict__ Out) {
  __shared__ alignas(16) ushort_t Ks[2][64 * 128];
  __shared__ alignas(16) ushort_t Vs[2][128 * 64];
  __shared__ alignas(16) ushort_t Ps[4][32 * 64];  // per wave: P[q=32][n=64], swizzled

  int x = blockIdx.x, y = blockIdx.y;
  int qi = (x & 1) ? (x >> 1) : (15 - (x >> 1));   // consecutive-x pairs sum to 15
  if (y & 16) qi = 15 - qi;                        // stride-256 pairs also sum to 15
  int q0 = qi * 128;
  int bh = y;
  int b = bh >> 4, h = bh & 15;
  const ushort_t* Qh = Q + (size_t)bh * S_ * HS_;
  const ushort_t* Kh = Kg + (size_t)bh * S_ * HS_;
  const ushort_t* Vh = Vt + (size_t)bh * HS_ * S_;
  const float* mk = mask + (size_t)b * S_;

  int tid = threadIdx.x;
  int wave = tid >> 6, lane = tid & 63, quad = lane >> 4, l16 = lane & 15;

  bf16x8 qf[2][4];
#pragma unroll
  for (int i = 0; i < 2; ++i)
#pragma unroll
    for (int kb = 0; kb < 4; ++kb)
      qf[i][kb] = *(const bf16x8*)(
          Qh + (size_t)(q0 + wave * 32 + i * 16 + l16) * HS_ + kb * 32 + quad * 8);

  f32x4 o[2][8];
#pragma unroll
  for (int i = 0; i < 2; ++i)
#pragma unroll
    for (int dt = 0; dt < 8; ++dt) o[i][dt] = (f32x4){0.f, 0.f, 0.f, 0.f};
  float mrow[2] = {-1e30f, -1e30f};
  float lrow[2] = {0.f, 0.f};

  int ntiles = q0 / 64 + 2;

#pragma unroll
  for (int j = 0; j < 4; ++j) {
    int ch = wave * 4 + j;
    {
      int p = ch * 64 + lane;
      int r = p >> 4, g = (p & 15) ^ (r & 15);
      gload16(Kh + (size_t)r * HS_ + g * 8, &Ks[0][ch * 512]);
    }
    {
      int p = ch * 64 + lane;
      int r = p >> 3, g = (p & 7) ^ (r & 7);
      gload16(Vh + (size_t)r * S_ + g * 8, &Vs[0][ch * 512]);
    }
  }

  for (int it = 0; it < ntiles; ++it) {
    int bsel = it & 1;
    int n0 = it * 64;
    __syncthreads();

    if (it + 1 < ntiles) {
      int n1 = n0 + 64;
#pragma unroll
      for (int j = 0; j < 4; ++j) {
        int ch = wave * 4 + j;
        {
          int p = ch * 64 + lane;
          int r = p >> 4, g = (p & 15) ^ (r & 15);
          gload16(Kh + (size_t)(n1 + r) * HS_ + g * 8, &Ks[bsel ^ 1][ch * 512]);
        }
        {
          int p = ch * 64 + lane;
          int r = p >> 3, g = (p & 7) ^ (r & 7);
          gload16(Vh + (size_t)r * S_ + n1 + g * 8, &Vs[bsel ^ 1][ch * 512]);
        }
      }
    }

    float4 mkv[4];
#pragma unroll
    for (int t = 0; t < 4; ++t)
      mkv[t] = *(const float4*)&mk[n0 + t * 16 + quad * 4];
    bool edge = (it >= ntiles - 2);

    f32x4 s2[4][2];
#pragma unroll
    for (int t = 0; t < 4; ++t) {
      bf16x8 kf[4];
#pragma unroll
      for (int kb = 0; kb < 4; ++kb)
        kf[kb] = *(const bf16x8*)&Ks[bsel][(((t * 16 + l16) * 16) + ((kb * 4 + quad) ^ l16)) * 8];
      __builtin_amdgcn_s_setprio(1);
#pragma unroll
      for (int i = 0; i < 2; ++i) {
        f32x4 a = (f32x4){0.f, 0.f, 0.f, 0.f};
#pragma unroll
        for (int kb = 0; kb < 4; ++kb)
          a = __builtin_amdgcn_mfma_f32_16x16x32_bf16(kf[kb], qf[i][kb], a, 0, 0, 0);
        s2[t][i] = a;
      }
      __builtin_amdgcn_s_setprio(0);
    }

#pragma unroll
    for (int i = 0; i < 2; ++i) {
      int qg = q0 + wave * 32 + i * 16 + l16;
      float mx = -1e30f;
#pragma unroll
      for (int t = 0; t < 4; ++t)
#pragma unroll
        for (int reg = 0; reg < 4; ++reg) {
          float v = s2[t][i][reg] + mkv[t][reg];
          if (edge && (n0 + t * 16 + quad * 4 + reg > qg)) v = -1e30f;
          s2[t][i][reg] = v;
          mx = fmaxf(mx, v);
        }
      mx = fmaxf(mx, __shfl_xor(mx, 16, 64));
      mx = fmaxf(mx, __shfl_xor(mx, 32, 64));
      // T13 defer-max: if no row in this wave-half grew past mrow+8, keep the old
      // max (P <= e^8) and skip the alpha rescale of o[] and lrow.
      bool defer = (mrow[i] > -1e29f) && __all(mx <= mrow[i] + 8.0f);
      float mnew, alpha;
      if (defer) {
        mnew = mrow[i];
      } else {
        mnew = fmaxf(mrow[i], mx);
        alpha = __expf(mrow[i] - mnew);
        mrow[i] = mnew;
      }
      float rs = 0.f;
#pragma unroll
      for (int t = 0; t < 4; ++t)
#pragma unroll
        for (int reg = 0; reg < 4; ++reg) {
          float p = __expf(s2[t][i][reg] - mnew);
          s2[t][i][reg] = p;
          rs += p;
        }
      rs += __shfl_xor(rs, 16, 64);
      rs += __shfl_xor(rs, 32, 64);
      if (defer) {
        lrow[i] += rs;
      } else {
        lrow[i] = lrow[i] * alpha + rs;
#pragma unroll
        for (int dt = 0; dt < 8; ++dt) o[i][dt] *= alpha;
      }

#pragma unroll
      for (int t = 0; t < 4; ++t) {
        ushort4 pk;
        pk.x = f2bf(s2[t][i][0]); pk.y = f2bf(s2[t][i][1]);
        pk.z = f2bf(s2[t][i][2]); pk.w = f2bf(s2[t][i][3]);
        *(ushort4*)((char*)&Ps[wave][0] + (i * 16 + l16) * 128 +
                    (((t * 2 + (quad >> 1)) ^ (l16 & 7)) * 16) + (quad & 1) * 8) = pk;
      }
    }
    __builtin_amdgcn_s_waitcnt(0xC07F);  // lgkmcnt(0)

    bf16x8 pf[2][2];
#pragma unroll
    for (int i = 0; i < 2; ++i)
#pragma unroll
      for (int kb = 0; kb < 2; ++kb)
        pf[i][kb] = *(const bf16x8*)((char*)&Ps[wave][0] + (i * 16 + l16) * 128 +
                                     (((kb * 4 + quad) ^ (l16 & 7)) * 16));
    __builtin_amdgcn_s_setprio(1);
#pragma unroll
    for (int dt = 0; dt < 8; ++dt) {
#pragma unroll
      for (int kb = 0; kb < 2; ++kb) {
        bf16x8 vf = *(const bf16x8*)&Vs[bsel][((dt * 16 + l16) * 8 + ((kb * 4 + quad) ^ (l16 & 7))) * 8];
#pragma unroll
        for (int i = 0; i < 2; ++i)
          o[i][dt] = __builtin_amdgcn_mfma_f32_16x16x32_bf16(vf, pf[i][kb], o[i][dt], 0, 0, 0);
      }
    }
    __builtin_amdgcn_s_setprio(0);
  }

  float invl[2] = {1.0f / lrow[0], 1.0f / lrow[1]};
#pragma unroll
  for (int i = 0; i < 2; ++i) {
    int qg = q0 + wave * 32 + i * 16 + l16;
#pragma unroll
    for (int dt = 0; dt < 8; ++dt) {
      ushort4 ov;
      ov.x = f2bf(o[i][dt][0] * invl[i]);
      ov.y = f2bf(o[i][dt][1] * invl[i]);
      ov.z = f2bf(o[i][dt][2] * invl[i]);
      ov.w = f2bf(o[i][dt][3] * invl[i]);
      *(ushort4*)&Out[((size_t)(b * S_ + qg)) * HID_ + h * HS_ + dt * 16 + quad * 4] = ov;
    }
  }
}

// ---------------- launcher ----------------

extern "C" void kernel_launch(void* const* d_in, const int* in_sizes, int n_in,
                              void* d_out, int out_size, void* d_ws, size_t ws_size,
                              hipStream_t stream) {
  const float* hs    = (const float*)d_in[0];
  const float* amask = (const float*)d_in[1];
  const int*   pids  = (const int*)d_in[2];
  const float* Wqkv  = (const float*)d_in[3];
  const float* bqkv  = (const float*)d_in[4];
  const float* Wd    = (const float*)d_in[5];
  const float* bd    = (const float*)d_in[6];
  float* out = (float*)d_out;

  // workspace layout (96 MB):
  //  [0,16M)   Xb (bf16 X) -> reused as attn after gemm_qkv
  //  [16,40M)  WqkvT   [40,48M) WdT
  //  [48,64M)  Qb      [64,80M)  Kb      [80,96M)  Vt
  char* ws = (char*)d_ws;
  ushort_t* Xb    = (ushort_t*)(ws);
  ushort_t* WqkvT = (ushort_t*)(ws + ((size_t)16 << 20));
  ushort_t* WdT   = (ushort_t*)(ws + ((size_t)40 << 20));
  ushort_t* Qb    = (ushort_t*)(ws + ((size_t)48 << 20));
  ushort_t* Kb    = (ushort_t*)(ws + ((size_t)64 << 20));
  ushort_t* Vt    = (ushort_t*)(ws + ((size_t)80 << 20));
  ushort_t* attn  = Xb;

  prep<<<8192, 256, 0, stream>>>(hs, Wqkv, Wd, Xb, WqkvT, WdT);
  gemm_qkv<<<dim3(N_QKV / 128, (B_ * S_) / 128), 256, 0, stream>>>(
      Xb, WqkvT, bqkv, pids, Qb, Kb, Vt);
  flash_attn<<<dim3(S_ / 128, B_ * H_), 256, 0, stream>>>(Qb, Kb, Vt, amask, attn);
  gemm_bt<0><<<dim3(HID_ / 128, (B_ * S_) / 128), 256, 0, stream>>>(
      attn, WdT, bd, d_out, B_ * S_, HID_, HID_);
  (void)out; (void)in_sizes; (void)n_in; (void)out_size; (void)ws_size;
}